// Round 4
// baseline (758.910 us; speedup 1.0000x reference)
//
#include <hip/hip_runtime.h>
#include <hip/hip_bf16.h>

// Problem constants: B=2, S=2048, H=1024, G=256, E=8, M=2048, TOP_K=2
#define T_TOK 4096      // B*S
#define N_PAIR 8192     // T_TOK * 2
#define H_DIM 1024
#define M_DIM 2048
#define E_NUM 8

// transpose tiling: 64k x 64n tiles
#define T_W1 4096       // (E*H/64)*(M/64)  = 128*32
#define T_W2 8192       // (E*M/64)*(M/64)  = 256*32
#define T_W3 4096       // (E*M/64)*(H/64)  = 256*16
#define T_ROUT 1024     // 4096 tokens / 4 waves

using bf16x8 = __attribute__((ext_vector_type(8))) short;
using f32x4  = __attribute__((ext_vector_type(4))) float;

__device__ __forceinline__ unsigned short f2bf(float f) {
    unsigned int u = __builtin_bit_cast(unsigned int, f);
    u += 0x7fffu + ((u >> 16) & 1u);   // RNE
    return (unsigned short)(u >> 16);
}
__device__ __forceinline__ float bf2f(unsigned short u) {
    return __builtin_bit_cast(float, (unsigned int)u << 16);
}

// async global->LDS, 16B per lane; LDS dest is wave-uniform base + lane*16
__device__ __forceinline__ void async16(const unsigned short* g, unsigned short* l) {
    __builtin_amdgcn_global_load_lds(
        (const __attribute__((address_space(1))) void*)g,
        (__attribute__((address_space(3))) void*)l, 16, 0, 0);
}

// ---- transpose-convert one 64k x 64n tile: W [E*K][N] fp32 -> Wt [E][N][K] bf16 ----
__device__ __forceinline__ void transpose_tile(const float* __restrict__ W,
                                               unsigned short* __restrict__ Wt,
                                               int tile, int K, int N,
                                               int kshift, int ntshift, char* smemraw)
{
    float (*ld)[68] = (float (*)[68])smemraw;       // 64 x 68 fp32 = 17.4 KB
    int r0 = (tile >> ntshift) * 64;                // row in [0, E*K)
    int n0 = (tile & ((1 << ntshift) - 1)) * 64;
    int t = threadIdx.x;
    {   // phase 1: 64 rows x 64 floats, 4 threads/row x 4 float4
        int row = t >> 2, c0 = t & 3;
        const float4* src = (const float4*)(W + (size_t)(r0 + row) * N + n0);
#pragma unroll
        for (int c = 0; c < 4; c++) {
            float4 v = src[c0 + 4 * c];
            float* d = &ld[row][(c0 + 4 * c) * 4];
            d[0] = v.x; d[1] = v.y; d[2] = v.z; d[3] = v.w;
        }
    }
    __syncthreads();
    {   // phase 2: 64 n-rows x 64 k bf16; 4 threads/n-row x 32B -> 128B runs
        int n = t >> 2, k0 = (t & 3) * 16;
        bf16x8 o0, o1;
#pragma unroll
        for (int q = 0; q < 8; q++) o0[q] = (short)f2bf(ld[k0 + q][n]);
#pragma unroll
        for (int q = 0; q < 8; q++) o1[q] = (short)f2bf(ld[k0 + 8 + q][n]);
        int e = r0 >> kshift;
        int k = (r0 & (K - 1)) + k0;
        unsigned short* dst = Wt + ((size_t)e * N + (n0 + n)) * K + k;
        *(bf16x8*)dst = o0;
        *(bf16x8*)(dst + 8) = o1;
    }
}

// ---- K_prep: W1 transpose (blocks [0,T_W1)) + routing (+ bf16 token copy xb) ----
__global__ void k_prep(const float* __restrict__ W1, unsigned short* __restrict__ W1t,
                       const float* __restrict__ x, const float* __restrict__ rms_w,
                       const float* __restrict__ wg_W, const float* __restrict__ genre,
                       const float* __restrict__ gg_W, const float* __restrict__ gg_b,
                       const float* __restrict__ wg_b,
                       int* __restrict__ tok_e, float* __restrict__ tok_w,
                       unsigned short* __restrict__ xb)
{
    __shared__ __align__(16) char smem[17408];
    int bid = blockIdx.x;

    if (bid < T_W1) {
        transpose_tile(W1, W1t, bid, H_DIM, M_DIM, 10, 5, smem);
        return;
    }

    // ---- routing: RMSNorm + word gate + genre gate + softmax + top2; write xb ----
    int wave = threadIdx.x >> 6, lane = threadIdx.x & 63;
    int tok = (bid - T_W1) * 4 + wave;
    int b = tok >> 11;
    const float* xr = x + (size_t)tok * H_DIM;
    unsigned short* xs = (unsigned short*)smem;     // 4 waves x 1024 shorts = 8 KB
    float xv[16];
    float ss = 0.f;
#pragma unroll
    for (int j = 0; j < 16; j++) { xv[j] = xr[lane + 64 * j]; ss += xv[j] * xv[j]; }
#pragma unroll
    for (int j = 0; j < 16; j++) xs[wave * 1024 + lane + 64 * j] = f2bf(xv[j]);
#pragma unroll
    for (int off = 32; off > 0; off >>= 1) ss += __shfl_xor(ss, off);
    float rstd = rsqrtf(ss * (1.f / 1024.f) + 1e-6f);
    float g[8] = {0.f, 0.f, 0.f, 0.f, 0.f, 0.f, 0.f, 0.f};
#pragma unroll
    for (int gi0 = 0; gi0 < 4; gi0++) {
        int gi = lane + gi0 * 64;
        float gf = genre[b * 256 + gi];
        const float4* w4 = (const float4*)(gg_W + gi * 8);
        float4 wa = w4[0], wb = w4[1];
        g[0] += gf * wa.x; g[1] += gf * wa.y; g[2] += gf * wa.z; g[3] += gf * wa.w;
        g[4] += gf * wb.x; g[5] += gf * wb.y; g[6] += gf * wb.z; g[7] += gf * wb.w;
    }
#pragma unroll
    for (int j = 0; j < 16; j++) {
        int h = lane + 64 * j;
        float xn = xv[j] * rstd * rms_w[h];
        const float4* w4 = (const float4*)(wg_W + h * 8);
        float4 wa = w4[0], wb = w4[1];
        g[0] += xn * wa.x; g[1] += xn * wa.y; g[2] += xn * wa.z; g[3] += xn * wa.w;
        g[4] += xn * wb.x; g[5] += xn * wb.y; g[6] += xn * wb.z; g[7] += xn * wb.w;
    }
#pragma unroll
    for (int e = 0; e < 8; e++) {
#pragma unroll
        for (int off = 32; off > 0; off >>= 1) g[e] += __shfl_xor(g[e], off);
    }
    __syncthreads();
    // coalesced bf16 row write: 64 lanes x 2x16B = 2 KB row
    {
        unsigned short* dst = xb + (size_t)tok * H_DIM;
        bf16x8 a0 = *(bf16x8*)&xs[wave * 1024 + lane * 16];
        bf16x8 a1 = *(bf16x8*)&xs[wave * 1024 + lane * 16 + 8];
        *(bf16x8*)(dst + lane * 16) = a0;
        *(bf16x8*)(dst + lane * 16 + 8) = a1;
    }
    if (lane == 0) {
#pragma unroll
        for (int e = 0; e < 8; e++) g[e] += wg_b[e] + gg_b[e];
        float m = g[0];
        for (int e = 1; e < 8; e++) m = fmaxf(m, g[e]);
        float p[8], psum = 0.f;
        for (int e = 0; e < 8; e++) { p[e] = expf(g[e] - m); psum += p[e]; }
        int i0 = 0;
        for (int e = 1; e < 8; e++) if (p[e] > p[i0]) i0 = e;
        int i1 = (i0 == 0) ? 1 : 0;
        for (int e = 0; e < 8; e++) if (e != i0 && p[e] > p[i1]) i1 = e;
        float inv = 1.f / psum;
        tok_e[tok * 2] = i0;         tok_e[tok * 2 + 1] = i1;
        tok_w[tok * 2] = p[i0] * inv; tok_w[tok * 2 + 1] = p[i1] * inv;
    }
}

// ---- K_scan: histogram + exclusive scan + perm/pair_pos build (single block) ----
__global__ void k_scan(const int* __restrict__ tok_e, int* __restrict__ meta,
                       int* __restrict__ perm, int* __restrict__ pair_pos)
{
    __shared__ int cnt[8], fill[8];
    int t = threadIdx.x;
    if (t < 8) cnt[t] = 0;
    __syncthreads();
    for (int p = t; p < N_PAIR; p += 256) atomicAdd(&cnt[tok_e[p]], 1);
    __syncthreads();
    if (t == 0) {
        int acc = 0;
        for (int e = 0; e < 8; e++) {
            meta[e] = cnt[e]; meta[8 + e] = acc; fill[e] = acc; acc += cnt[e];
        }
    }
    __syncthreads();
    for (int p = t; p < N_PAIR; p += 256) {
        int e = tok_e[p];
        int pos = atomicAdd(&fill[e], 1);
        perm[pos] = p >> 1;       // token index
        pair_pos[p] = pos;
    }
}

// ---- K_mlp1: fused GEMM1 (A via perm indirection from xb) + W2/W3 transposes ----
// id&3==3 -> GEMM1 block (4096); else transpose block (12288). Interleaved so
// MFMA-bound and HBM-bound blocks are co-resident (m114 overlap).
__global__ void k_mlp1(const float* __restrict__ W2, const float* __restrict__ W3,
                       unsigned short* __restrict__ W2t, unsigned short* __restrict__ W3t,
                       const unsigned short* __restrict__ xb,
                       const unsigned short* __restrict__ W1t,
                       const float* __restrict__ b1, unsigned short* __restrict__ h1,
                       const int* __restrict__ meta, const int* __restrict__ perm)
{
    __shared__ __align__(16) char smem[32768];
    int id = blockIdx.x;
    int sel = id & 3;
    if (sel != 3) {
        int t_idx = (id >> 2) * 3 + sel;            // 0..12287
        if (t_idx < T_W2) transpose_tile(W2, W2t, t_idx, M_DIM, M_DIM, 11, 5, smem);
        else              transpose_tile(W3, W3t, t_idx - T_W2, M_DIM, H_DIM, 11, 4, smem);
        return;
    }
    int g = id >> 2;                                 // 0..4095
    int bx = g & 15, by = (g >> 4) & 31, e = g >> 9;
    int cnt = meta[e];
    if (by * 128 >= cnt) return;
    int base = meta[8 + e];
    const int K = H_DIM, N = M_DIM;

    unsigned short* As = (unsigned short*)smem;            // 128*64
    unsigned short* Bs = (unsigned short*)(smem + 16384);  // 128*64

    int tid = threadIdx.x;
    int wave = tid >> 6, lane = tid & 63;
    int lrow8 = lane >> 3;
    int lslot = lane & 7;
    int chunk_g = (lslot ^ lrow8) * 8;

    const unsigned short* Bw = W1t + (size_t)e * N * K + (size_t)(bx * 128) * K;
    const unsigned short* gA[4]; const unsigned short* gB[4];
    unsigned short* lA[4]; unsigned short* lB[4];
#pragma unroll
    for (int c = 0; c < 4; c++) {
        int rloc = wave * 32 + c * 8 + lrow8;
        int grow = by * 128 + rloc;
        int tok = (grow < cnt) ? perm[base + grow] : 0;   // clamp; discarded in epilogue
        gA[c] = xb + (size_t)tok * K + chunk_g;
        gB[c] = Bw + (size_t)rloc * K + chunk_g;
        lA[c] = &As[(wave * 32 + c * 8) * 64];
        lB[c] = &Bs[(wave * 32 + c * 8) * 64];
    }

    int wr = (wave >> 1) * 64, wc = (wave & 1) * 64;
    int lm = lane & 15, lq = lane >> 4;
    int aoff[4][2], boff[4][2];
#pragma unroll
    for (int i = 0; i < 4; i++)
#pragma unroll
        for (int h = 0; h < 2; h++) {
            int R = wr + i * 16 + lm;
            aoff[i][h] = R * 64 + (((h * 4 + lq) ^ (R & 7)) * 8);
            int Nn = wc + i * 16 + lm;
            boff[i][h] = Nn * 64 + (((h * 4 + lq) ^ (Nn & 7)) * 8);
        }

    f32x4 acc[4][4] = {};
    for (int kt = 0; kt < K; kt += 64) {
#pragma unroll
        for (int c = 0; c < 4; c++) { async16(gA[c] + kt, lA[c]); async16(gB[c] + kt, lB[c]); }
        __syncthreads();
#pragma unroll
        for (int h = 0; h < 2; h++) {
            bf16x8 af[4], bfr[4];
#pragma unroll
            for (int i = 0; i < 4; i++) af[i] = *(const bf16x8*)&As[aoff[i][h]];
#pragma unroll
            for (int j = 0; j < 4; j++) bfr[j] = *(const bf16x8*)&Bs[boff[j][h]];
#pragma unroll
            for (int i = 0; i < 4; i++)
#pragma unroll
                for (int j = 0; j < 4; j++)
                    acc[i][j] = __builtin_amdgcn_mfma_f32_16x16x32_bf16(af[i], bfr[j], acc[i][j], 0, 0, 0);
        }
        __syncthreads();
    }

#pragma unroll
    for (int j = 0; j < 4; j++) {
        int n = bx * 128 + wc + j * 16 + lm;
        float bv = b1[(size_t)e * N + n];
#pragma unroll
        for (int i = 0; i < 4; i++) {
#pragma unroll
            for (int r = 0; r < 4; r++) {
                int grow = by * 128 + wr + i * 16 + lq * 4 + r;
                if (grow < cnt) {
                    float v = fmaxf(acc[i][j][r] + bv, 0.f);
                    h1[(size_t)(base + grow) * N + n] = f2bf(v);
                }
            }
        }
    }
}

// ---- GEMM (2/3): C = A_seg @ Wt[e]^T (+bias, optional relu), bf16 out ----
template<bool RELU>
__global__ void k_gemm(const unsigned short* __restrict__ A,
                       const unsigned short* __restrict__ Wt,
                       const float* __restrict__ bias,
                       unsigned short* __restrict__ C,
                       const int* __restrict__ meta,
                       int K, int N)
{
    int e = blockIdx.z;
    int cnt = meta[e];
    int by = blockIdx.y;
    if (by * 128 >= cnt) return;
    int base = meta[8 + e];
    int bx = blockIdx.x;

    __shared__ __align__(16) unsigned short As[128 * 64];
    __shared__ __align__(16) unsigned short Bs[128 * 64];

    int tid = threadIdx.x;
    int wave = tid >> 6, lane = tid & 63;
    int lrow8 = lane >> 3;
    int lslot = lane & 7;
    int chunk_g = (lslot ^ lrow8) * 8;

    const unsigned short* Bw = Wt + (size_t)e * N * K + (size_t)(bx * 128) * K;
    const unsigned short* gA[4]; const unsigned short* gB[4];
    unsigned short* lA[4]; unsigned short* lB[4];
#pragma unroll
    for (int c = 0; c < 4; c++) {
        int rloc = wave * 32 + c * 8 + lrow8;
        int ra = base + by * 128 + rloc;
        ra = min(ra, N_PAIR - 1);               // clamp: garbage rows discarded
        gA[c] = A + (size_t)ra * K + chunk_g;
        gB[c] = Bw + (size_t)rloc * K + chunk_g;
        lA[c] = &As[(wave * 32 + c * 8) * 64];
        lB[c] = &Bs[(wave * 32 + c * 8) * 64];
    }

    int wr = (wave >> 1) * 64, wc = (wave & 1) * 64;
    int lm = lane & 15, lq = lane >> 4;
    int aoff[4][2], boff[4][2];
#pragma unroll
    for (int i = 0; i < 4; i++)
#pragma unroll
        for (int h = 0; h < 2; h++) {
            int R = wr + i * 16 + lm;
            aoff[i][h] = R * 64 + (((h * 4 + lq) ^ (R & 7)) * 8);
            int Nn = wc + i * 16 + lm;
            boff[i][h] = Nn * 64 + (((h * 4 + lq) ^ (Nn & 7)) * 8);
        }

    f32x4 acc[4][4] = {};
    for (int kt = 0; kt < K; kt += 64) {
#pragma unroll
        for (int c = 0; c < 4; c++) { async16(gA[c] + kt, lA[c]); async16(gB[c] + kt, lB[c]); }
        __syncthreads();
#pragma unroll
        for (int h = 0; h < 2; h++) {
            bf16x8 af[4], bfr[4];
#pragma unroll
            for (int i = 0; i < 4; i++) af[i] = *(const bf16x8*)&As[aoff[i][h]];
#pragma unroll
            for (int j = 0; j < 4; j++) bfr[j] = *(const bf16x8*)&Bs[boff[j][h]];
#pragma unroll
            for (int i = 0; i < 4; i++)
#pragma unroll
                for (int j = 0; j < 4; j++)
                    acc[i][j] = __builtin_amdgcn_mfma_f32_16x16x32_bf16(af[i], bfr[j], acc[i][j], 0, 0, 0);
        }
        __syncthreads();
    }

#pragma unroll
    for (int j = 0; j < 4; j++) {
        int n = bx * 128 + wc + j * 16 + lm;
        float bv = bias[(size_t)e * N + n];
#pragma unroll
        for (int i = 0; i < 4; i++) {
#pragma unroll
            for (int r = 0; r < 4; r++) {
                int grow = by * 128 + wr + i * 16 + lq * 4 + r;
                if (grow < cnt) {
                    float v = acc[i][j][r] + bv;
                    if (RELU) v = fmaxf(v, 0.f);
                    C[(size_t)(base + grow) * N + n] = f2bf(v);
                }
            }
        }
    }
}

// ---- K_combine: out[t] = w0*o3[pos(t,0)] + w1*o3[pos(t,1)] (o3 bf16) ----
__global__ void k_combine(const unsigned short* __restrict__ o3,
                          const int* __restrict__ pair_pos,
                          const float* __restrict__ tok_w, float* __restrict__ out)
{
    int t = blockIdx.x;
    int c = threadIdx.x;
    int p0 = pair_pos[t * 2], p1 = pair_pos[t * 2 + 1];
    float w0 = tok_w[t * 2], w1 = tok_w[t * 2 + 1];
    ushort4 a = ((const ushort4*)(o3 + (size_t)p0 * H_DIM))[c];
    ushort4 bq = ((const ushort4*)(o3 + (size_t)p1 * H_DIM))[c];
    float4 o;
    o.x = w0 * bf2f(a.x) + w1 * bf2f(bq.x);
    o.y = w0 * bf2f(a.y) + w1 * bf2f(bq.y);
    o.z = w0 * bf2f(a.z) + w1 * bf2f(bq.z);
    o.w = w0 * bf2f(a.w) + w1 * bf2f(bq.w);
    ((float4*)(out + (size_t)t * H_DIM))[c] = o;
}

extern "C" void kernel_launch(void* const* d_in, const int* in_sizes, int n_in,
                              void* d_out, int out_size, void* d_ws, size_t ws_size,
                              hipStream_t stream) {
    const float* x      = (const float*)d_in[0];
    const float* genre  = (const float*)d_in[1];
    const float* rms_w  = (const float*)d_in[2];
    const float* wg_W   = (const float*)d_in[3];
    const float* wg_b   = (const float*)d_in[4];
    const float* gg_W   = (const float*)d_in[5];
    const float* gg_b   = (const float*)d_in[6];
    const float* W1     = (const float*)d_in[7];
    const float* b1     = (const float*)d_in[8];
    const float* W2     = (const float*)d_in[9];
    const float* b2     = (const float*)d_in[10];
    const float* W3     = (const float*)d_in[11];
    const float* b3     = (const float*)d_in[12];
    float* out = (float*)d_out;

    char* p = (char*)d_ws;
    auto alloc = [&](size_t bytes) { char* r = p; p += (bytes + 255) & ~(size_t)255; return r; };
    unsigned short* W1t = (unsigned short*)alloc((size_t)E_NUM * H_DIM * M_DIM * 2);
    unsigned short* W2t = (unsigned short*)alloc((size_t)E_NUM * M_DIM * M_DIM * 2);
    unsigned short* W3t = (unsigned short*)alloc((size_t)E_NUM * M_DIM * H_DIM * 2);
    unsigned short* xb  = (unsigned short*)alloc((size_t)T_TOK * H_DIM * 2);
    unsigned short* h1  = (unsigned short*)alloc((size_t)N_PAIR * M_DIM * 2);
    unsigned short* h2  = (unsigned short*)alloc((size_t)N_PAIR * M_DIM * 2);
    unsigned short* o3  = (unsigned short*)alloc((size_t)N_PAIR * H_DIM * 2);
    int*   meta         = (int*)alloc(16 * 4);      // counts[8], bases[8]
    int*   tok_e        = (int*)alloc((size_t)N_PAIR * 4);
    float* tok_w        = (float*)alloc((size_t)N_PAIR * 4);
    int*   perm         = (int*)alloc((size_t)N_PAIR * 4);
    int*   pair_pos     = (int*)alloc((size_t)N_PAIR * 4);

    dim3 blk(256);

    k_prep<<<T_W1 + T_ROUT, blk, 0, stream>>>(
        W1, W1t, x, rms_w, wg_W, genre, gg_W, gg_b, wg_b, tok_e, tok_w, xb);
    k_scan<<<1, blk, 0, stream>>>(tok_e, meta, perm, pair_pos);
    k_mlp1<<<16384, blk, 0, stream>>>(W2, W3, W2t, W3t, xb, W1t, b1, h1, meta, perm);
    k_gemm<true ><<<dim3(M_DIM / 128, 32, E_NUM), blk, 0, stream>>>(
        h1, W2t, b2, h2, meta, M_DIM, M_DIM);
    k_gemm<false><<<dim3(H_DIM / 128, 32, E_NUM), blk, 0, stream>>>(
        h2, W3t, b3, o3, meta, M_DIM, H_DIM);
    k_combine<<<T_TOK, blk, 0, stream>>>(o3, pair_pos, tok_w, out);

    (void)in_sizes; (void)n_in; (void)ws_size;
}